// Round 3
// baseline (740.029 us; speedup 1.0000x reference)
//
#include <hip/hip_runtime.h>
#include <stdint.h>

#define FF 128

typedef __attribute__((ext_vector_type(8))) short bf8_t;     // 8 x bf16 MFMA frag
typedef __attribute__((ext_vector_type(4))) float f4_t;      // MFMA acc
typedef __attribute__((ext_vector_type(8))) uint16_t us8_t;  // 8 x bf16 bits

__device__ __forceinline__ uint16_t f2bf(float f) {
  union { float f; uint32_t u; } v; v.f = f;
  return (uint16_t)((v.u + 0x7fffu + ((v.u >> 16) & 1u)) >> 16);  // RNE
}
__device__ __forceinline__ float bf2f(uint16_t h) {
  union { uint32_t u; float f; } v; v.u = ((uint32_t)h) << 16;
  return v.f;
}

// ---------------- weights f32 -> bf16 ----------------
// layout: [wsl | w1n | w2n | w1d | w2d] each 128x128, then wgat 128x384
__global__ __launch_bounds__(256) void cvt_w_k(
    const float* __restrict__ wsl, const float* __restrict__ w1n,
    const float* __restrict__ w2n, const float* __restrict__ w1d,
    const float* __restrict__ w2d, const float* __restrict__ wgat,
    uint16_t* __restrict__ o) {
  int i = blockIdx.x * 256 + threadIdx.x;
  const int NW = 5 * 16384;
  if (i >= NW + 49152) return;
  float v;
  if (i < NW) {
    int wsel = i >> 14, j = i & 16383;
    const float* p = (wsel == 0) ? wsl : (wsel == 1) ? w1n : (wsel == 2) ? w2n
                     : (wsel == 3) ? w1d : w2d;
    v = p[j];
  } else {
    v = wgat[i - NW];
  }
  o[i] = f2bf(v);
}

// ---------------- x f32 -> bf16 ----------------
__global__ __launch_bounds__(256) void cvt_x_k(const float* __restrict__ x,
                                               uint16_t* __restrict__ xb, int n4) {
  int i = blockIdx.x * 256 + threadIdx.x;
  if (i >= n4) return;
  float4 v = ((const float4*)x)[i];
  uint2 o;
  o.x = ((uint32_t)f2bf(v.y) << 16) | f2bf(v.x);
  o.y = ((uint32_t)f2bf(v.w) << 16) | f2bf(v.z);
  ((uint2*)xb)[i] = o;
}

// ---------------- counting sort of edges by key = dst*2 + type ----------------
__global__ __launch_bounds__(256) void hist_k(const int* __restrict__ dst,
                                              const int* __restrict__ ety,
                                              int* __restrict__ hist, int E) {
  int i = blockIdx.x * 256 + threadIdx.x;
  if (i < E) atomicAdd(&hist[(dst[i] << 1) | ety[i]], 1);
}

__global__ __launch_bounds__(256) void scan1_k(const int* __restrict__ hist,
                                               int* __restrict__ off,
                                               int* __restrict__ bsum, int nbins) {
  int i = blockIdx.x * 256 + threadIdx.x;
  int v = (i < nbins) ? hist[i] : 0;
  int lane = threadIdx.x & 63, w = threadIdx.x >> 6;
  int s = v;
#pragma unroll
  for (int d = 1; d < 64; d <<= 1) {
    int o = __shfl_up(s, (unsigned)d, 64);
    if (lane >= d) s += o;
  }
  __shared__ int wsum[4];
  if (lane == 63) wsum[w] = s;
  __syncthreads();
  int add = 0;
  for (int k = 0; k < w; ++k) add += wsum[k];
  s += add;
  if (i < nbins) off[i] = s - v;  // exclusive
  if (threadIdx.x == 255) bsum[blockIdx.x] = s;
}

__global__ __launch_bounds__(1024) void scan2_k(int* __restrict__ bsum, int nb) {
  int t = threadIdx.x;
  int v = (t < nb) ? bsum[t] : 0;
  int lane = t & 63, w = t >> 6;
  int s = v;
#pragma unroll
  for (int d = 1; d < 64; d <<= 1) {
    int o = __shfl_up(s, (unsigned)d, 64);
    if (lane >= d) s += o;
  }
  __shared__ int ws[16];
  if (lane == 63) ws[w] = s;
  __syncthreads();
  int add = 0;
  for (int k = 0; k < w; ++k) add += ws[k];
  s += add;
  if (t < nb) bsum[t] = s - v;
}

__global__ __launch_bounds__(256) void scan3_k(int* __restrict__ off,
                                               int* __restrict__ cur,
                                               const int* __restrict__ bsum,
                                               int nbins, int E) {
  int i = blockIdx.x * 256 + threadIdx.x;
  if (i < nbins) {
    int v = off[i] + bsum[blockIdx.x];
    off[i] = v;
    cur[i] = v;
  }
  if (i == nbins) off[i] = E;
}

__global__ __launch_bounds__(256) void sctidx_k(const int* __restrict__ src,
                                                const int* __restrict__ dst,
                                                const int* __restrict__ ety,
                                                int* __restrict__ cur,
                                                int* __restrict__ ssrc, int E) {
  int i = blockIdx.x * 256 + threadIdx.x;
  if (i < E) {
    int pos = atomicAdd(&cur[(dst[i] << 1) | ety[i]], 1);
    ssrc[pos] = src[i];
  }
}

// ---------------- segment-sum (bf16 gather) + own row: emits bf16 (x+agg) ----------------
__global__ __launch_bounds__(256) void agg_k(const int* __restrict__ off,
                                             const int* __restrict__ ssrc,
                                             const uint16_t* __restrict__ xb,
                                             const float* __restrict__ x,
                                             uint16_t* __restrict__ xanb,
                                             uint16_t* __restrict__ xadb, int nbins) {
  int wid = (blockIdx.x * 256 + threadIdx.x) >> 6;
  int lane = threadIdx.x & 63;
  if (wid >= nbins) return;
  int e = off[wid], end = off[wid + 1];
  float ax = 0.f, ay = 0.f;
  for (; e < end; ++e) {
    int s = ssrc[e];
    uint32_t v = ((const uint32_t*)(xb + (size_t)s * FF))[lane];
    ax += bf2f((uint16_t)(v & 0xffffu));
    ay += bf2f((uint16_t)(v >> 16));
  }
  int n = wid >> 1;
  float2 xo = ((const float2*)(x + (size_t)n * FF))[lane];
  ax += xo.x;
  ay += xo.y;
  uint32_t o = ((uint32_t)f2bf(ay) << 16) | f2bf(ax);
  uint16_t* dstp = (wid & 1) ? xadb : xanb;
  ((uint32_t*)(dstp + (size_t)n * FF))[lane] = o;
}

// ---------------- stage 1: three GEMMs (A bf16 direct), 32 rows/wave ----------------
__global__ __launch_bounds__(256) void gemm1_k(
    const uint16_t* __restrict__ xb, const uint16_t* __restrict__ xanb,
    const uint16_t* __restrict__ xadb, const uint16_t* __restrict__ wbf,
    const float* __restrict__ b_sl, const float* __restrict__ b1n,
    const float* __restrict__ b1d, float* __restrict__ xnx,
    uint16_t* __restrict__ h1n, uint16_t* __restrict__ h1d,
    float* __restrict__ gstats, int N) {
  __shared__ float sstat[4][4][128];
  const int tid = threadIdx.x;
  const int lane = tid & 63, w = tid >> 6;
  const int lr = lane & 15, lg = lane >> 4;
  const int rowbase = blockIdx.x * 128 + w * 32;
  const int arow0 = min(rowbase + lr, N - 1);
  const int arow1 = min(rowbase + 16 + lr, N - 1);

  f4_t acc[2][8];
  const f4_t zz = {0.f, 0.f, 0.f, 0.f};

#pragma unroll 1
  for (int gi = 0; gi < 3; ++gi) {
    const uint16_t* ap = (gi == 0) ? xb : (gi == 1) ? xanb : xadb;
    const uint16_t* wp = wbf + ((gi == 0) ? 0 : (gi == 1) ? 1 : 3) * 16384;
#pragma unroll
    for (int rg = 0; rg < 2; ++rg)
#pragma unroll
      for (int t = 0; t < 8; ++t) acc[rg][t] = zz;
#pragma unroll
    for (int s = 0; s < 4; ++s) {
      const int k0 = s * 32 + lg * 8;
      bf8_t a0 = *(const bf8_t*)(ap + (size_t)arow0 * FF + k0);
      bf8_t a1 = *(const bf8_t*)(ap + (size_t)arow1 * FF + k0);
#pragma unroll
      for (int t = 0; t < 8; ++t) {
        bf8_t b = *(const bf8_t*)(wp + (size_t)(t * 16 + lr) * FF + k0);
        acc[0][t] = __builtin_amdgcn_mfma_f32_16x16x32_bf16(a0, b, acc[0][t], 0, 0, 0);
        acc[1][t] = __builtin_amdgcn_mfma_f32_16x16x32_bf16(a1, b, acc[1][t], 0, 0, 0);
      }
    }
    if (gi == 0) {
#pragma unroll
      for (int t = 0; t < 8; ++t) {
        const int col = t * 16 + lr;
        const float b = b_sl[col];
#pragma unroll
        for (int rg = 0; rg < 2; ++rg)
#pragma unroll
          for (int r = 0; r < 4; ++r) {
            const int row = rowbase + rg * 16 + lg * 4 + r;
            if (row < N) xnx[(size_t)row * FF + col] = acc[rg][t][r] + b;
          }
      }
    } else {
      const float* bp = (gi == 1) ? b1n : b1d;
      uint16_t* hp = (gi == 1) ? h1n : h1d;
#pragma unroll
      for (int t = 0; t < 8; ++t) {
        const int col = t * 16 + lr;
        const float b = bp[col];
        float sum = 0.f, ss = 0.f;
#pragma unroll
        for (int rg = 0; rg < 2; ++rg)
#pragma unroll
          for (int r = 0; r < 4; ++r) {
            const int row = rowbase + rg * 16 + lg * 4 + r;
            const float h = acc[rg][t][r] + b;
            if (row < N) {
              hp[(size_t)row * FF + col] = f2bf(h);
              sum += h;
              ss += h * h;
            }
          }
        sum += __shfl_xor(sum, 16, 64);
        sum += __shfl_xor(sum, 32, 64);
        ss += __shfl_xor(ss, 16, 64);
        ss += __shfl_xor(ss, 32, 64);
        if (lane < 16) {
          sstat[w][(gi - 1) * 2 + 0][col] = sum;
          sstat[w][(gi - 1) * 2 + 1][col] = ss;
        }
      }
    }
  }
  __syncthreads();
  for (int i = tid; i < 512; i += 256) {
    int a = i >> 7, c = i & 127;
    float v = sstat[0][a][c] + sstat[1][a][c] + sstat[2][a][c] + sstat[3][a][c];
    unsafeAtomicAdd(&gstats[i], v);
  }
}

// ---------------- BN finalize ----------------
__global__ void bnfin_k(const float* __restrict__ gstats,
                        const float* __restrict__ gamn, const float* __restrict__ betn,
                        const float* __restrict__ gamd, const float* __restrict__ betd,
                        float* __restrict__ bnp, int N) {
  int i = threadIdx.x;  // 128
  float invN = 1.f / (float)N;
  {
    float mu = gstats[i] * invN;
    float var = gstats[128 + i] * invN - mu * mu;
    float sc = gamn[i] * rsqrtf(var + 1e-5f);
    bnp[i] = sc;
    bnp[128 + i] = betn[i] - mu * sc;
  }
  {
    float mu = gstats[256 + i] * invN;
    float var = gstats[384 + i] * invN - mu * mu;
    float sc = gamd[i] * rsqrtf(var + 1e-5f);
    bnp[256 + i] = sc;
    bnp[384 + i] = betd[i] - mu * sc;
  }
}

// ---------------- stage 2: BN+ReLU, GEMM2, gate GEMM, softmax+cumsum, out ----------------
__global__ __launch_bounds__(256) void fuse2_k(
    const uint16_t* __restrict__ h1n, const uint16_t* __restrict__ h1d,
    const float* __restrict__ xnx, const uint16_t* __restrict__ wbf,
    const float* __restrict__ bnp, const float* __restrict__ b2n,
    const float* __restrict__ b2d, const float* __restrict__ bgat,
    float* __restrict__ out, int N) {
  __shared__ __align__(16) uint16_t smt[4][2][32][136];  // per-wave bf16 xn/xd tiles
  const int tid = threadIdx.x;
  const int lane = tid & 63, w = tid >> 6;
  const int lr = lane & 15, lg = lane >> 4;
  const int rowbase = blockIdx.x * 128 + w * 32;
  const int arow0 = min(rowbase + lr, N - 1);
  const int arow1 = min(rowbase + 16 + lr, N - 1);
  const uint16_t* wg = wbf + 5 * 16384;

  f4_t accN[2][8], accG[2][8];
  const f4_t zz = {0.f, 0.f, 0.f, 0.f};

  // ---- branch GEMMs: h2 = relu(bn(h1)) @ w2.T + b2 ----
#pragma unroll
  for (int br = 0; br < 2; ++br) {
    const uint16_t* hp = br ? h1d : h1n;
    const float* bnb = bnp + br * 256;
    const uint16_t* wp = wbf + (br ? 4 : 2) * 16384;
    const float* bp = br ? b2d : b2n;
    f4_t(&acc)[2][8] = br ? accG : accN;
#pragma unroll
    for (int rg = 0; rg < 2; ++rg)
#pragma unroll
      for (int t = 0; t < 8; ++t) acc[rg][t] = zz;
#pragma unroll
    for (int s = 0; s < 4; ++s) {
      const int k0 = s * 32 + lg * 8;
      f4_t sc0 = *(const f4_t*)(bnb + k0), sc1 = *(const f4_t*)(bnb + k0 + 4);
      f4_t sh0 = *(const f4_t*)(bnb + 128 + k0), sh1 = *(const f4_t*)(bnb + 128 + k0 + 4);
      us8_t h0 = *(const us8_t*)(hp + (size_t)arow0 * FF + k0);
      us8_t h1 = *(const us8_t*)(hp + (size_t)arow1 * FF + k0);
      bf8_t a0, a1;
#pragma unroll
      for (int j = 0; j < 4; ++j) {
        a0[j] = (short)f2bf(fmaxf(bf2f(h0[j]) * sc0[j] + sh0[j], 0.f));
        a0[j + 4] = (short)f2bf(fmaxf(bf2f(h0[j + 4]) * sc1[j] + sh1[j], 0.f));
        a1[j] = (short)f2bf(fmaxf(bf2f(h1[j]) * sc0[j] + sh0[j], 0.f));
        a1[j + 4] = (short)f2bf(fmaxf(bf2f(h1[j + 4]) * sc1[j] + sh1[j], 0.f));
      }
#pragma unroll
      for (int t = 0; t < 8; ++t) {
        bf8_t b = *(const bf8_t*)(wp + (size_t)(t * 16 + lr) * FF + k0);
        acc[0][t] = __builtin_amdgcn_mfma_f32_16x16x32_bf16(a0, b, acc[0][t], 0, 0, 0);
        acc[1][t] = __builtin_amdgcn_mfma_f32_16x16x32_bf16(a1, b, acc[1][t], 0, 0, 0);
      }
    }
#pragma unroll
    for (int t = 0; t < 8; ++t) {
      const int col = t * 16 + lr;
      const float b = bp[col];
#pragma unroll
      for (int rg = 0; rg < 2; ++rg)
#pragma unroll
        for (int r = 0; r < 4; ++r) {
          float h = acc[rg][t][r] + b;
          acc[rg][t][r] = h;  // keep f32 xn in regs (accN) for epilogue
          smt[w][br][rg * 16 + lg * 4 + r][col] = f2bf(h);
        }
    }
  }
  __syncthreads();

  // ---- gate logits = [xx|xn|xd] @ wgat.T ----
#pragma unroll
  for (int rg = 0; rg < 2; ++rg)
#pragma unroll
    for (int t = 0; t < 8; ++t) accG[rg][t] = zz;

#pragma unroll
  for (int src = 0; src < 3; ++src) {
#pragma unroll
    for (int s = 0; s < 4; ++s) {
      const int k0 = s * 32 + lg * 8;
      bf8_t a0, a1;
      if (src == 0) {
        f4_t p0 = *(const f4_t*)(xnx + (size_t)arow0 * FF + k0);
        f4_t p1 = *(const f4_t*)(xnx + (size_t)arow0 * FF + k0 + 4);
        f4_t q0 = *(const f4_t*)(xnx + (size_t)arow1 * FF + k0);
        f4_t q1 = *(const f4_t*)(xnx + (size_t)arow1 * FF + k0 + 4);
#pragma unroll
        for (int j = 0; j < 4; ++j) {
          a0[j] = (short)f2bf(p0[j]);
          a0[j + 4] = (short)f2bf(p1[j]);
          a1[j] = (short)f2bf(q0[j]);
          a1[j + 4] = (short)f2bf(q1[j]);
        }
      } else {
        a0 = *(const bf8_t*)&smt[w][src - 1][lr][k0];
        a1 = *(const bf8_t*)&smt[w][src - 1][16 + lr][k0];
      }
#pragma unroll
      for (int t = 0; t < 8; ++t) {
        bf8_t b = *(const bf8_t*)(wg + (size_t)(t * 16 + lr) * 384 + src * FF + k0);
        accG[0][t] = __builtin_amdgcn_mfma_f32_16x16x32_bf16(a0, b, accG[0][t], 0, 0, 0);
        accG[1][t] = __builtin_amdgcn_mfma_f32_16x16x32_bf16(a1, b, accG[1][t], 0, 0, 0);
      }
    }
  }

  // ---- per-row softmax + cumsum + output ----
#pragma unroll 1
  for (int rg = 0; rg < 2; ++rg) {
#pragma unroll
    for (int r = 0; r < 4; ++r) {
      float lv[8];
#pragma unroll
      for (int t = 0; t < 8; ++t) lv[t] = accG[rg][t][r] + bgat[t * 16 + lr];
      float m = lv[0];
#pragma unroll
      for (int t = 1; t < 8; ++t) m = fmaxf(m, lv[t]);
#pragma unroll
      for (int d = 1; d < 16; d <<= 1) m = fmaxf(m, __shfl_xor(m, d, 16));
      float g[8];
      float run = 0.f;
#pragma unroll
      for (int t = 0; t < 8; ++t) {
        float p = __expf(lv[t] - m);
        float scn = p;
#pragma unroll
        for (int d = 1; d < 16; d <<= 1) {
          float o = __shfl_up(scn, (unsigned)d, 16);
          if (lr >= d) scn += o;
        }
        g[t] = run + scn;
        run += __shfl(scn, 15, 16);
      }
      const float inv = 1.f / run;
      const int row = rowbase + rg * 16 + lg * 4 + r;
      if (row < N) {
#pragma unroll
        for (int t = 0; t < 8; ++t) {
          const int col = t * 16 + lr;
          const float gat = g[t] * inv;
          const float xx = xnx[(size_t)row * FF + col];
          const float xn = accN[rg][t][r];
          const float xdf = bf2f(smt[w][1][rg * 16 + lg * 4 + r][127 - col]);
          out[(size_t)row * FF + col] = xx + xn + xdf * gat;
        }
      }
    }
  }
}

extern "C" void kernel_launch(void* const* d_in, const int* in_sizes, int n_in,
                              void* d_out, int out_size, void* d_ws, size_t ws_size,
                              hipStream_t stream) {
  const float* x = (const float*)d_in[0];
  const int* eidx = (const int*)d_in[1];
  const int* etype = (const int*)d_in[2];
  const float* w_sl = (const float*)d_in[3];
  const float* b_sl = (const float*)d_in[4];
  const float* w1n = (const float*)d_in[5];
  const float* b1n = (const float*)d_in[6];
  const float* gamn = (const float*)d_in[7];
  const float* betn = (const float*)d_in[8];
  const float* w2n = (const float*)d_in[9];
  const float* b2n = (const float*)d_in[10];
  const float* w1d = (const float*)d_in[11];
  const float* b1d = (const float*)d_in[12];
  const float* gamd = (const float*)d_in[13];
  const float* betd = (const float*)d_in[14];
  const float* w2d = (const float*)d_in[15];
  const float* b2d = (const float*)d_in[16];
  const float* wgat = (const float*)d_in[17];
  const float* bgat = (const float*)d_in[18];
  float* out = (float*)d_out;

  const int N = in_sizes[0] / FF;
  const int E = in_sizes[2];
  const int* src = eidx;
  const int* dst = eidx + E;
  const int nbins = 2 * N;

  const size_t NF = (size_t)N * FF;
  float* xnx = (float*)d_ws;
  float* gstats = xnx + NF;
  float* bnp = gstats + 512;
  uint16_t* wbf = (uint16_t*)(bnp + 512);      // 131072 u16
  uint16_t* xb = wbf + 131072;                 // NF
  uint16_t* xanb = xb + NF;
  uint16_t* xadb = xanb + NF;
  uint16_t* h1n = xadb + NF;
  uint16_t* h1d = h1n + NF;
  int* hist = (int*)(h1d + NF);
  int* off = hist + nbins;      // nbins+1
  int* cur = off + nbins + 1;   // nbins
  int* bsum = cur + nbins;      // <=1024
  int* ssrc = bsum + 1024;      // E

  const int nb1 = (nbins + 255) / 256;

  hipMemsetAsync(hist, 0, (size_t)nbins * sizeof(int), stream);
  hipMemsetAsync(gstats, 0, 512 * sizeof(float), stream);
  cvt_w_k<<<512, 256, 0, stream>>>(w_sl, w1n, w2n, w1d, w2d, wgat, wbf);
  cvt_x_k<<<(int)((NF / 4 + 255) / 256), 256, 0, stream>>>(x, xb, (int)(NF / 4));

  hist_k<<<(E + 255) / 256, 256, 0, stream>>>(dst, etype, hist, E);
  scan1_k<<<nb1, 256, 0, stream>>>(hist, off, bsum, nbins);
  scan2_k<<<1, 1024, 0, stream>>>(bsum, nb1);
  scan3_k<<<(nbins + 256) / 256, 256, 0, stream>>>(off, cur, bsum, nbins, E);
  sctidx_k<<<(E + 255) / 256, 256, 0, stream>>>(src, dst, etype, cur, ssrc, E);
  agg_k<<<(nbins + 3) / 4, 256, 0, stream>>>(off, ssrc, xb, x, xanb, xadb, nbins);

  const int nb = (N + 127) / 128;
  gemm1_k<<<nb, 256, 0, stream>>>(xb, xanb, xadb, wbf, b_sl, b1n, b1d, xnx, h1n,
                                  h1d, gstats, N);
  bnfin_k<<<1, 128, 0, stream>>>(gstats, gamn, betn, gamd, betd, bnp, N);
  fuse2_k<<<nb, 256, 0, stream>>>(h1n, h1d, xnx, wbf, bnp, b2n, b2d, bgat, out, N);
}

// Round 4
// 592.167 us; speedup vs baseline: 1.2497x; 1.2497x over previous
//
#include <hip/hip_runtime.h>
#include <stdint.h>

#define FF 128

typedef __attribute__((ext_vector_type(8))) short bf8_t;     // 8 x bf16 MFMA frag
typedef __attribute__((ext_vector_type(4))) float f4_t;      // MFMA acc
typedef __attribute__((ext_vector_type(8))) uint16_t us8_t;  // 8 x bf16 bits

__device__ __forceinline__ uint16_t f2bf(float f) {
  union { float f; uint32_t u; } v; v.f = f;
  return (uint16_t)((v.u + 0x7fffu + ((v.u >> 16) & 1u)) >> 16);  // RNE
}
__device__ __forceinline__ float bf2f(uint16_t h) {
  union { uint32_t u; float f; } v; v.u = ((uint32_t)h) << 16;
  return v.f;
}

// ---------------- weights f32 -> bf16 ----------------
// layout: [wsl | w1n | w2n | w1d | w2d] each 128x128, then wgat 128x384
__global__ __launch_bounds__(256) void cvt_w_k(
    const float* __restrict__ wsl, const float* __restrict__ w1n,
    const float* __restrict__ w2n, const float* __restrict__ w1d,
    const float* __restrict__ w2d, const float* __restrict__ wgat,
    uint16_t* __restrict__ o) {
  int i = blockIdx.x * 256 + threadIdx.x;
  const int NW = 5 * 16384;
  if (i >= NW + 49152) return;
  float v;
  if (i < NW) {
    int wsel = i >> 14, j = i & 16383;
    const float* p = (wsel == 0) ? wsl : (wsel == 1) ? w1n : (wsel == 2) ? w2n
                     : (wsel == 3) ? w1d : w2d;
    v = p[j];
  } else {
    v = wgat[i - NW];
  }
  o[i] = f2bf(v);
}

// ---------------- x f32 -> bf16 ----------------
__global__ __launch_bounds__(256) void cvt_x_k(const float* __restrict__ x,
                                               uint16_t* __restrict__ xb, int n4) {
  int i = blockIdx.x * 256 + threadIdx.x;
  if (i >= n4) return;
  float4 v = ((const float4*)x)[i];
  uint2 o;
  o.x = ((uint32_t)f2bf(v.y) << 16) | f2bf(v.x);
  o.y = ((uint32_t)f2bf(v.w) << 16) | f2bf(v.z);
  ((uint2*)xb)[i] = o;
}

// ---------------- counting sort of edges by key = dst*2 + type ----------------
__global__ __launch_bounds__(256) void hist_k(const int* __restrict__ dst,
                                              const int* __restrict__ ety,
                                              int* __restrict__ hist, int E) {
  int i = blockIdx.x * 256 + threadIdx.x;
  if (i < E) atomicAdd(&hist[(dst[i] << 1) | ety[i]], 1);
}

__global__ __launch_bounds__(256) void scan1_k(const int* __restrict__ hist,
                                               int* __restrict__ off,
                                               int* __restrict__ bsum, int nbins) {
  int i = blockIdx.x * 256 + threadIdx.x;
  int v = (i < nbins) ? hist[i] : 0;
  int lane = threadIdx.x & 63, w = threadIdx.x >> 6;
  int s = v;
#pragma unroll
  for (int d = 1; d < 64; d <<= 1) {
    int o = __shfl_up(s, (unsigned)d, 64);
    if (lane >= d) s += o;
  }
  __shared__ int wsum[4];
  if (lane == 63) wsum[w] = s;
  __syncthreads();
  int add = 0;
  for (int k = 0; k < w; ++k) add += wsum[k];
  s += add;
  if (i < nbins) off[i] = s - v;  // exclusive
  if (threadIdx.x == 255) bsum[blockIdx.x] = s;
}

__global__ __launch_bounds__(1024) void scan2_k(int* __restrict__ bsum, int nb) {
  int t = threadIdx.x;
  int v = (t < nb) ? bsum[t] : 0;
  int lane = t & 63, w = t >> 6;
  int s = v;
#pragma unroll
  for (int d = 1; d < 64; d <<= 1) {
    int o = __shfl_up(s, (unsigned)d, 64);
    if (lane >= d) s += o;
  }
  __shared__ int ws[16];
  if (lane == 63) ws[w] = s;
  __syncthreads();
  int add = 0;
  for (int k = 0; k < w; ++k) add += ws[k];
  s += add;
  if (t < nb) bsum[t] = s - v;
}

__global__ __launch_bounds__(256) void scan3_k(int* __restrict__ off,
                                               int* __restrict__ cur,
                                               const int* __restrict__ bsum,
                                               int nbins, int E) {
  int i = blockIdx.x * 256 + threadIdx.x;
  if (i < nbins) {
    int v = off[i] + bsum[blockIdx.x];
    off[i] = v;
    cur[i] = v;
  }
  if (i == nbins) off[i] = E;
}

__global__ __launch_bounds__(256) void sctidx_k(const int* __restrict__ src,
                                                const int* __restrict__ dst,
                                                const int* __restrict__ ety,
                                                int* __restrict__ cur,
                                                int* __restrict__ ssrc, int E) {
  int i = blockIdx.x * 256 + threadIdx.x;
  if (i < E) {
    int pos = atomicAdd(&cur[(dst[i] << 1) | ety[i]], 1);
    ssrc[pos] = src[i];
  }
}

// ---------------- segment-sum (bf16 gather) + own row: emits bf16 (x+agg) ----------------
__global__ __launch_bounds__(256) void agg_k(const int* __restrict__ off,
                                             const int* __restrict__ ssrc,
                                             const uint16_t* __restrict__ xb,
                                             const float* __restrict__ x,
                                             uint16_t* __restrict__ xanb,
                                             uint16_t* __restrict__ xadb, int nbins) {
  int wid = (blockIdx.x * 256 + threadIdx.x) >> 6;
  int lane = threadIdx.x & 63;
  if (wid >= nbins) return;
  int e = off[wid], end = off[wid + 1];
  float ax = 0.f, ay = 0.f;
  // 2-deep unroll: two independent row loads in flight per iteration
  for (; e + 1 < end; e += 2) {
    int s0 = ssrc[e], s1 = ssrc[e + 1];
    uint32_t v0 = ((const uint32_t*)(xb + (size_t)s0 * FF))[lane];
    uint32_t v1 = ((const uint32_t*)(xb + (size_t)s1 * FF))[lane];
    ax += bf2f((uint16_t)(v0 & 0xffffu)) + bf2f((uint16_t)(v1 & 0xffffu));
    ay += bf2f((uint16_t)(v0 >> 16)) + bf2f((uint16_t)(v1 >> 16));
  }
  if (e < end) {
    int s0 = ssrc[e];
    uint32_t v0 = ((const uint32_t*)(xb + (size_t)s0 * FF))[lane];
    ax += bf2f((uint16_t)(v0 & 0xffffu));
    ay += bf2f((uint16_t)(v0 >> 16));
  }
  int n = wid >> 1;
  float2 xo = ((const float2*)(x + (size_t)n * FF))[lane];
  ax += xo.x;
  ay += xo.y;
  uint32_t o = ((uint32_t)f2bf(ay) << 16) | f2bf(ax);
  uint16_t* dstp = (wid & 1) ? xadb : xanb;
  ((uint32_t*)(dstp + (size_t)n * FF))[lane] = o;
}

// ---------------- stage 1: branch GEMM1s (A bf16 direct), 32 rows/wave + BN stats ----------------
__global__ __launch_bounds__(256) void gemm1_k(
    const uint16_t* __restrict__ xanb, const uint16_t* __restrict__ xadb,
    const uint16_t* __restrict__ wbf, const float* __restrict__ b1n,
    const float* __restrict__ b1d, uint16_t* __restrict__ h1n,
    uint16_t* __restrict__ h1d, float* __restrict__ gstats, int N) {
  __shared__ float sstat[4][4][128];
  const int tid = threadIdx.x;
  const int lane = tid & 63, w = tid >> 6;
  const int lr = lane & 15, lg = lane >> 4;
  const int rowbase = blockIdx.x * 128 + w * 32;
  const int arow0 = min(rowbase + lr, N - 1);
  const int arow1 = min(rowbase + 16 + lr, N - 1);

  f4_t acc[2][8];
  const f4_t zz = {0.f, 0.f, 0.f, 0.f};

#pragma unroll 1
  for (int gi = 0; gi < 2; ++gi) {
    const uint16_t* ap = gi ? xadb : xanb;
    const uint16_t* wp = wbf + (gi ? 3 : 1) * 16384;
#pragma unroll
    for (int rg = 0; rg < 2; ++rg)
#pragma unroll
      for (int t = 0; t < 8; ++t) acc[rg][t] = zz;
#pragma unroll
    for (int s = 0; s < 4; ++s) {
      const int k0 = s * 32 + lg * 8;
      bf8_t a0 = *(const bf8_t*)(ap + (size_t)arow0 * FF + k0);
      bf8_t a1 = *(const bf8_t*)(ap + (size_t)arow1 * FF + k0);
#pragma unroll
      for (int t = 0; t < 8; ++t) {
        bf8_t b = *(const bf8_t*)(wp + (size_t)(t * 16 + lr) * FF + k0);
        acc[0][t] = __builtin_amdgcn_mfma_f32_16x16x32_bf16(a0, b, acc[0][t], 0, 0, 0);
        acc[1][t] = __builtin_amdgcn_mfma_f32_16x16x32_bf16(a1, b, acc[1][t], 0, 0, 0);
      }
    }
    const float* bp = gi ? b1d : b1n;
    uint16_t* hp = gi ? h1d : h1n;
#pragma unroll
    for (int t = 0; t < 8; ++t) {
      const int col = t * 16 + lr;
      const float b = bp[col];
      float sum = 0.f, ss = 0.f;
#pragma unroll
      for (int rg = 0; rg < 2; ++rg)
#pragma unroll
        for (int r = 0; r < 4; ++r) {
          const int row = rowbase + rg * 16 + lg * 4 + r;
          const float h = acc[rg][t][r] + b;
          if (row < N) {
            hp[(size_t)row * FF + col] = f2bf(h);
            sum += h;
            ss += h * h;
          }
        }
      sum += __shfl_xor(sum, 16, 64);
      sum += __shfl_xor(sum, 32, 64);
      ss += __shfl_xor(ss, 16, 64);
      ss += __shfl_xor(ss, 32, 64);
      if (lane < 16) {
        sstat[w][gi * 2 + 0][col] = sum;
        sstat[w][gi * 2 + 1][col] = ss;
      }
    }
  }
  __syncthreads();
  for (int i = tid; i < 512; i += 256) {
    int a = i >> 7, c = i & 127;
    float v = sstat[0][a][c] + sstat[1][a][c] + sstat[2][a][c] + sstat[3][a][c];
    unsafeAtomicAdd(&gstats[i], v);
  }
}

// ---------------- BN finalize ----------------
__global__ void bnfin_k(const float* __restrict__ gstats,
                        const float* __restrict__ gamn, const float* __restrict__ betn,
                        const float* __restrict__ gamd, const float* __restrict__ betd,
                        float* __restrict__ bnp, int N) {
  int i = threadIdx.x;  // 128
  float invN = 1.f / (float)N;
  {
    float mu = gstats[i] * invN;
    float var = gstats[128 + i] * invN - mu * mu;
    float sc = gamn[i] * rsqrtf(var + 1e-5f);
    bnp[i] = sc;
    bnp[128 + i] = betn[i] - mu * sc;
  }
  {
    float mu = gstats[256 + i] * invN;
    float var = gstats[384 + i] * invN - mu * mu;
    float sc = gamd[i] * rsqrtf(var + 1e-5f);
    bnp[256 + i] = sc;
    bnp[384 + i] = betd[i] - mu * sc;
  }
}

// ---------------- stage 2: xx GEMM, BN+ReLU+GEMM2 (both), gate GEMM, softmax, out ----------------
// 16 rows/wave, one accumulator set live at a time, wave-private bf16 LDS tiles.
__global__ __launch_bounds__(256) void fuse2_k(
    const uint16_t* __restrict__ xb, const uint16_t* __restrict__ h1n,
    const uint16_t* __restrict__ h1d, const uint16_t* __restrict__ wbf,
    const float* __restrict__ bnp, const float* __restrict__ b_sl,
    const float* __restrict__ b2n, const float* __restrict__ b2d,
    const float* __restrict__ bgat, float* __restrict__ out, int N) {
  __shared__ __align__(16) uint16_t smt[4][3][16][136];  // per-wave xx/xn/xd tiles
  const int tid = threadIdx.x;
  const int lane = tid & 63, w = tid >> 6;
  const int lr = lane & 15, lg = lane >> 4;
  const int rowbase = blockIdx.x * 64 + w * 16;
  const int arow = min(rowbase + lr, N - 1);
  const uint16_t* wg = wbf + 5 * 16384;

  f4_t acc[8];
  const f4_t zz = {0.f, 0.f, 0.f, 0.f};

  // ---- xx = xb @ wsl.T + b_sl -> LDS tile 0 ----
#pragma unroll
  for (int t = 0; t < 8; ++t) acc[t] = zz;
#pragma unroll
  for (int s = 0; s < 4; ++s) {
    const int k0 = s * 32 + lg * 8;
    bf8_t a = *(const bf8_t*)(xb + (size_t)arow * FF + k0);
#pragma unroll
    for (int t = 0; t < 8; ++t) {
      bf8_t b = *(const bf8_t*)(wbf + (size_t)(t * 16 + lr) * FF + k0);
      acc[t] = __builtin_amdgcn_mfma_f32_16x16x32_bf16(a, b, acc[t], 0, 0, 0);
    }
  }
#pragma unroll
  for (int t = 0; t < 8; ++t) {
    const int col = t * 16 + lr;
    const float b = b_sl[col];
#pragma unroll
    for (int r = 0; r < 4; ++r) smt[w][0][lg * 4 + r][col] = f2bf(acc[t][r] + b);
  }

  // ---- branches: relu(bn(h1)) @ w2.T + b2 -> LDS tiles 1,2 ----
#pragma unroll 1
  for (int br = 0; br < 2; ++br) {
    const uint16_t* hp = br ? h1d : h1n;
    const float* bnb = bnp + br * 256;
    const uint16_t* wp = wbf + (br ? 4 : 2) * 16384;
    const float* bp = br ? b2d : b2n;
#pragma unroll
    for (int t = 0; t < 8; ++t) acc[t] = zz;
#pragma unroll
    for (int s = 0; s < 4; ++s) {
      const int k0 = s * 32 + lg * 8;
      f4_t sc0 = *(const f4_t*)(bnb + k0), sc1 = *(const f4_t*)(bnb + k0 + 4);
      f4_t sh0 = *(const f4_t*)(bnb + 128 + k0), sh1 = *(const f4_t*)(bnb + 128 + k0 + 4);
      us8_t h = *(const us8_t*)(hp + (size_t)arow * FF + k0);
      bf8_t a;
#pragma unroll
      for (int j = 0; j < 4; ++j) {
        a[j] = (short)f2bf(fmaxf(bf2f(h[j]) * sc0[j] + sh0[j], 0.f));
        a[j + 4] = (short)f2bf(fmaxf(bf2f(h[j + 4]) * sc1[j] + sh1[j], 0.f));
      }
#pragma unroll
      for (int t = 0; t < 8; ++t) {
        bf8_t b = *(const bf8_t*)(wp + (size_t)(t * 16 + lr) * FF + k0);
        acc[t] = __builtin_amdgcn_mfma_f32_16x16x32_bf16(a, b, acc[t], 0, 0, 0);
      }
    }
#pragma unroll
    for (int t = 0; t < 8; ++t) {
      const int col = t * 16 + lr;
      const float b = bp[col];
#pragma unroll
      for (int r = 0; r < 4; ++r) smt[w][1 + br][lg * 4 + r][col] = f2bf(acc[t][r] + b);
    }
  }
  // no __syncthreads: tiles are wave-private; lgkmcnt ordering is within-wave

  // ---- gate logits = [xx|xn|xd] @ wgat.T ----
#pragma unroll
  for (int t = 0; t < 8; ++t) acc[t] = zz;
#pragma unroll 1
  for (int src = 0; src < 3; ++src) {
#pragma unroll
    for (int s = 0; s < 4; ++s) {
      const int k0 = s * 32 + lg * 8;
      bf8_t a = *(const bf8_t*)&smt[w][src][lr][k0];
#pragma unroll
      for (int t = 0; t < 8; ++t) {
        bf8_t b = *(const bf8_t*)(wg + (size_t)(t * 16 + lr) * 384 + src * FF + k0);
        acc[t] = __builtin_amdgcn_mfma_f32_16x16x32_bf16(a, b, acc[t], 0, 0, 0);
      }
    }
  }

  // ---- per-row softmax + cumsum + output ----
#pragma unroll
  for (int r = 0; r < 4; ++r) {
    float lv[8];
#pragma unroll
    for (int t = 0; t < 8; ++t) lv[t] = acc[t][r] + bgat[t * 16 + lr];
    float m = lv[0];
#pragma unroll
    for (int t = 1; t < 8; ++t) m = fmaxf(m, lv[t]);
#pragma unroll
    for (int d = 1; d < 16; d <<= 1) m = fmaxf(m, __shfl_xor(m, d, 16));
    float g[8];
    float run = 0.f;
#pragma unroll
    for (int t = 0; t < 8; ++t) {
      float p = __expf(lv[t] - m);
      float scn = p;
#pragma unroll
      for (int d = 1; d < 16; d <<= 1) {
        float o = __shfl_up(scn, (unsigned)d, 16);
        if (lr >= d) scn += o;
      }
      g[t] = run + scn;
      run += __shfl(scn, 15, 16);
    }
    const float inv = 1.f / run;
    const int row = rowbase + lg * 4 + r;
    if (row < N) {
      const int lrow = lg * 4 + r;
#pragma unroll
      for (int t = 0; t < 8; ++t) {
        const int col = t * 16 + lr;
        const float gat = g[t] * inv;
        const float xx = bf2f(smt[w][0][lrow][col]);
        const float xn = bf2f(smt[w][1][lrow][col]);
        const float xdf = bf2f(smt[w][2][lrow][127 - col]);
        out[(size_t)row * FF + col] = xx + xn + xdf * gat;
      }
    }
  }
}

extern "C" void kernel_launch(void* const* d_in, const int* in_sizes, int n_in,
                              void* d_out, int out_size, void* d_ws, size_t ws_size,
                              hipStream_t stream) {
  const float* x = (const float*)d_in[0];
  const int* eidx = (const int*)d_in[1];
  const int* etype = (const int*)d_in[2];
  const float* w_sl = (const float*)d_in[3];
  const float* b_sl = (const float*)d_in[4];
  const float* w1n = (const float*)d_in[5];
  const float* b1n = (const float*)d_in[6];
  const float* gamn = (const float*)d_in[7];
  const float* betn = (const float*)d_in[8];
  const float* w2n = (const float*)d_in[9];
  const float* b2n = (const float*)d_in[10];
  const float* w1d = (const float*)d_in[11];
  const float* b1d = (const float*)d_in[12];
  const float* gamd = (const float*)d_in[13];
  const float* betd = (const float*)d_in[14];
  const float* w2d = (const float*)d_in[15];
  const float* b2d = (const float*)d_in[16];
  const float* wgat = (const float*)d_in[17];
  const float* bgat = (const float*)d_in[18];
  float* out = (float*)d_out;

  const int N = in_sizes[0] / FF;
  const int E = in_sizes[2];
  const int* src = eidx;
  const int* dst = eidx + E;
  const int nbins = 2 * N;

  const size_t NF = (size_t)N * FF;
  float* gstats = (float*)d_ws;
  float* bnp = gstats + 512;
  uint16_t* wbf = (uint16_t*)(bnp + 512);  // 131072 u16
  uint16_t* xb = wbf + 131072;             // NF
  uint16_t* xanb = xb + NF;
  uint16_t* xadb = xanb + NF;
  uint16_t* h1n = xadb + NF;
  uint16_t* h1d = h1n + NF;
  int* hist = (int*)(h1d + NF);
  int* off = hist + nbins;     // nbins+1
  int* cur = off + nbins + 1;  // nbins
  int* bsum = cur + nbins;     // <=1024
  int* ssrc = bsum + 1024;     // E

  const int nb1 = (nbins + 255) / 256;

  hipMemsetAsync(hist, 0, (size_t)nbins * sizeof(int), stream);
  hipMemsetAsync(gstats, 0, 512 * sizeof(float), stream);
  cvt_w_k<<<512, 256, 0, stream>>>(w_sl, w1n, w2n, w1d, w2d, wgat, wbf);
  cvt_x_k<<<(int)((NF / 4 + 255) / 256), 256, 0, stream>>>(x, xb, (int)(NF / 4));

  hist_k<<<(E + 255) / 256, 256, 0, stream>>>(dst, etype, hist, E);
  scan1_k<<<nb1, 256, 0, stream>>>(hist, off, bsum, nbins);
  scan2_k<<<1, 1024, 0, stream>>>(bsum, nb1);
  scan3_k<<<(nbins + 256) / 256, 256, 0, stream>>>(off, cur, bsum, nbins, E);
  sctidx_k<<<(E + 255) / 256, 256, 0, stream>>>(src, dst, etype, cur, ssrc, E);
  agg_k<<<(nbins + 3) / 4, 256, 0, stream>>>(off, ssrc, xb, x, xanb, xadb, nbins);

  gemm1_k<<<(N + 127) / 128, 256, 0, stream>>>(xanb, xadb, wbf, b1n, b1d, h1n, h1d,
                                               gstats, N);
  bnfin_k<<<1, 128, 0, stream>>>(gstats, gamn, betn, gamd, betd, bnp, N);
  fuse2_k<<<(N + 63) / 64, 256, 0, stream>>>(xb, h1n, h1d, wbf, bnp, b_sl, b2n, b2d,
                                             bgat, out, N);
}

// Round 5
// 580.070 us; speedup vs baseline: 1.2758x; 1.0209x over previous
//
#include <hip/hip_runtime.h>
#include <stdint.h>

#define FF 128

typedef __attribute__((ext_vector_type(8))) short bf8_t;     // 8 x bf16 MFMA frag
typedef __attribute__((ext_vector_type(4))) float f4_t;      // MFMA acc
typedef __attribute__((ext_vector_type(8))) uint16_t us8_t;  // 8 x bf16 bits

__device__ __forceinline__ uint16_t f2bf(float f) {
  union { float f; uint32_t u; } v; v.f = f;
  return (uint16_t)((v.u + 0x7fffu + ((v.u >> 16) & 1u)) >> 16);  // RNE
}
__device__ __forceinline__ float bf2f(uint16_t h) {
  union { uint32_t u; float f; } v; v.u = ((uint32_t)h) << 16;
  return v.f;
}

// ---------------- weights f32 -> bf16 ----------------
// layout: [wsl | w1n | w2n | w1d | w2d] each 128x128, then wgat 128x384
__global__ __launch_bounds__(256) void cvt_w_k(
    const float* __restrict__ wsl, const float* __restrict__ w1n,
    const float* __restrict__ w2n, const float* __restrict__ w1d,
    const float* __restrict__ w2d, const float* __restrict__ wgat,
    uint16_t* __restrict__ o) {
  int i = blockIdx.x * 256 + threadIdx.x;
  const int NW = 5 * 16384;
  if (i >= NW + 49152) return;
  float v;
  if (i < NW) {
    int wsel = i >> 14, j = i & 16383;
    const float* p = (wsel == 0) ? wsl : (wsel == 1) ? w1n : (wsel == 2) ? w2n
                     : (wsel == 3) ? w1d : w2d;
    v = p[j];
  } else {
    v = wgat[i - NW];
  }
  o[i] = f2bf(v);
}

// ---------------- x f32 -> bf16 ----------------
__global__ __launch_bounds__(256) void cvt_x_k(const float* __restrict__ x,
                                               uint16_t* __restrict__ xb, int n4) {
  int i = blockIdx.x * 256 + threadIdx.x;
  if (i >= n4) return;
  float4 v = ((const float4*)x)[i];
  uint2 o;
  o.x = ((uint32_t)f2bf(v.y) << 16) | f2bf(v.x);
  o.y = ((uint32_t)f2bf(v.w) << 16) | f2bf(v.z);
  ((uint2*)xb)[i] = o;
}

// ---------------- counting sort of edges by key = dst*2 + type ----------------
__global__ __launch_bounds__(256) void hist_k(const int* __restrict__ dst,
                                              const int* __restrict__ ety,
                                              int* __restrict__ hist, int E) {
  int i = blockIdx.x * 256 + threadIdx.x;
  if (i < E) atomicAdd(&hist[(dst[i] << 1) | ety[i]], 1);
}

__global__ __launch_bounds__(256) void scan1_k(const int* __restrict__ hist,
                                               int* __restrict__ off,
                                               int* __restrict__ bsum, int nbins) {
  int i = blockIdx.x * 256 + threadIdx.x;
  int v = (i < nbins) ? hist[i] : 0;
  int lane = threadIdx.x & 63, w = threadIdx.x >> 6;
  int s = v;
#pragma unroll
  for (int d = 1; d < 64; d <<= 1) {
    int o = __shfl_up(s, (unsigned)d, 64);
    if (lane >= d) s += o;
  }
  __shared__ int wsum[4];
  if (lane == 63) wsum[w] = s;
  __syncthreads();
  int add = 0;
  for (int k = 0; k < w; ++k) add += wsum[k];
  s += add;
  if (i < nbins) off[i] = s - v;  // exclusive
  if (threadIdx.x == 255) bsum[blockIdx.x] = s;
}

__global__ __launch_bounds__(1024) void scan2_k(int* __restrict__ bsum, int nb) {
  int t = threadIdx.x;
  int v = (t < nb) ? bsum[t] : 0;
  int lane = t & 63, w = t >> 6;
  int s = v;
#pragma unroll
  for (int d = 1; d < 64; d <<= 1) {
    int o = __shfl_up(s, (unsigned)d, 64);
    if (lane >= d) s += o;
  }
  __shared__ int ws[16];
  if (lane == 63) ws[w] = s;
  __syncthreads();
  int add = 0;
  for (int k = 0; k < w; ++k) add += ws[k];
  s += add;
  if (t < nb) bsum[t] = s - v;
}

__global__ __launch_bounds__(256) void scan3_k(int* __restrict__ off,
                                               int* __restrict__ cur,
                                               const int* __restrict__ bsum,
                                               int nbins, int E) {
  int i = blockIdx.x * 256 + threadIdx.x;
  if (i < nbins) {
    int v = off[i] + bsum[blockIdx.x];
    off[i] = v;
    cur[i] = v;
  }
  if (i == nbins) off[i] = E;
}

__global__ __launch_bounds__(256) void sctidx_k(const int* __restrict__ src,
                                                const int* __restrict__ dst,
                                                const int* __restrict__ ety,
                                                int* __restrict__ cur,
                                                int* __restrict__ ssrc, int E) {
  int i = blockIdx.x * 256 + threadIdx.x;
  if (i < E) {
    int pos = atomicAdd(&cur[(dst[i] << 1) | ety[i]], 1);
    ssrc[pos] = src[i];
  }
}

// ---------------- segment-sum (bf16 gather) + own row: emits bf16 (x+agg) ----------------
__global__ __launch_bounds__(256) void agg_k(const int* __restrict__ off,
                                             const int* __restrict__ ssrc,
                                             const uint16_t* __restrict__ xb,
                                             const float* __restrict__ x,
                                             uint16_t* __restrict__ xanb,
                                             uint16_t* __restrict__ xadb, int nbins) {
  int wid = (blockIdx.x * 256 + threadIdx.x) >> 6;
  int lane = threadIdx.x & 63;
  if (wid >= nbins) return;
  int e = off[wid], end = off[wid + 1];
  float ax = 0.f, ay = 0.f, bx = 0.f, by = 0.f;
  // 4-deep unroll, dual accumulators: 4 independent row loads in flight
  for (; e + 3 < end; e += 4) {
    int s0 = ssrc[e], s1 = ssrc[e + 1], s2 = ssrc[e + 2], s3 = ssrc[e + 3];
    uint32_t v0 = ((const uint32_t*)(xb + (size_t)s0 * FF))[lane];
    uint32_t v1 = ((const uint32_t*)(xb + (size_t)s1 * FF))[lane];
    uint32_t v2 = ((const uint32_t*)(xb + (size_t)s2 * FF))[lane];
    uint32_t v3 = ((const uint32_t*)(xb + (size_t)s3 * FF))[lane];
    ax += bf2f((uint16_t)(v0 & 0xffffu)) + bf2f((uint16_t)(v2 & 0xffffu));
    ay += bf2f((uint16_t)(v0 >> 16)) + bf2f((uint16_t)(v2 >> 16));
    bx += bf2f((uint16_t)(v1 & 0xffffu)) + bf2f((uint16_t)(v3 & 0xffffu));
    by += bf2f((uint16_t)(v1 >> 16)) + bf2f((uint16_t)(v3 >> 16));
  }
  for (; e < end; ++e) {
    int s0 = ssrc[e];
    uint32_t v0 = ((const uint32_t*)(xb + (size_t)s0 * FF))[lane];
    ax += bf2f((uint16_t)(v0 & 0xffffu));
    ay += bf2f((uint16_t)(v0 >> 16));
  }
  ax += bx;
  ay += by;
  int n = wid >> 1;
  float2 xo = ((const float2*)(x + (size_t)n * FF))[lane];
  ax += xo.x;
  ay += xo.y;
  uint32_t o = ((uint32_t)f2bf(ay) << 16) | f2bf(ax);
  uint16_t* dstp = (wid & 1) ? xadb : xanb;
  ((uint32_t*)(dstp + (size_t)n * FF))[lane] = o;
}

// ---------------- stage 1: branch GEMM1s (A bf16 direct), 32 rows/wave + BN stats ----------------
__global__ __launch_bounds__(256) void gemm1_k(
    const uint16_t* __restrict__ xanb, const uint16_t* __restrict__ xadb,
    const uint16_t* __restrict__ wbf, const float* __restrict__ b1n,
    const float* __restrict__ b1d, uint16_t* __restrict__ h1n,
    uint16_t* __restrict__ h1d, float* __restrict__ gstats, int N) {
  __shared__ float sstat[4][4][128];
  const int tid = threadIdx.x;
  const int lane = tid & 63, w = tid >> 6;
  const int lr = lane & 15, lg = lane >> 4;
  const int rowbase = blockIdx.x * 128 + w * 32;
  const int arow0 = min(rowbase + lr, N - 1);
  const int arow1 = min(rowbase + 16 + lr, N - 1);

  f4_t acc[2][8];
  const f4_t zz = {0.f, 0.f, 0.f, 0.f};

#pragma unroll 1
  for (int gi = 0; gi < 2; ++gi) {
    const uint16_t* ap = gi ? xadb : xanb;
    const uint16_t* wp = wbf + (gi ? 3 : 1) * 16384;
#pragma unroll
    for (int rg = 0; rg < 2; ++rg)
#pragma unroll
      for (int t = 0; t < 8; ++t) acc[rg][t] = zz;
#pragma unroll
    for (int s = 0; s < 4; ++s) {
      const int k0 = s * 32 + lg * 8;
      bf8_t a0 = *(const bf8_t*)(ap + (size_t)arow0 * FF + k0);
      bf8_t a1 = *(const bf8_t*)(ap + (size_t)arow1 * FF + k0);
#pragma unroll
      for (int t = 0; t < 8; ++t) {
        bf8_t b = *(const bf8_t*)(wp + (size_t)(t * 16 + lr) * FF + k0);
        acc[0][t] = __builtin_amdgcn_mfma_f32_16x16x32_bf16(a0, b, acc[0][t], 0, 0, 0);
        acc[1][t] = __builtin_amdgcn_mfma_f32_16x16x32_bf16(a1, b, acc[1][t], 0, 0, 0);
      }
    }
    const float* bp = gi ? b1d : b1n;
    uint16_t* hp = gi ? h1d : h1n;
#pragma unroll
    for (int t = 0; t < 8; ++t) {
      const int col = t * 16 + lr;
      const float b = bp[col];
      float sum = 0.f, ss = 0.f;
#pragma unroll
      for (int rg = 0; rg < 2; ++rg)
#pragma unroll
        for (int r = 0; r < 4; ++r) {
          const int row = rowbase + rg * 16 + lg * 4 + r;
          const float h = acc[rg][t][r] + b;
          if (row < N) {
            hp[(size_t)row * FF + col] = f2bf(h);
            sum += h;
            ss += h * h;
          }
        }
      sum += __shfl_xor(sum, 16, 64);
      sum += __shfl_xor(sum, 32, 64);
      ss += __shfl_xor(ss, 16, 64);
      ss += __shfl_xor(ss, 32, 64);
      if (lane < 16) {
        sstat[w][gi * 2 + 0][col] = sum;
        sstat[w][gi * 2 + 1][col] = ss;
      }
    }
  }
  __syncthreads();
  for (int i = tid; i < 512; i += 256) {
    int a = i >> 7, c = i & 127;
    float v = sstat[0][a][c] + sstat[1][a][c] + sstat[2][a][c] + sstat[3][a][c];
    unsafeAtomicAdd(&gstats[i], v);
  }
}

// ---------------- BN finalize ----------------
__global__ void bnfin_k(const float* __restrict__ gstats,
                        const float* __restrict__ gamn, const float* __restrict__ betn,
                        const float* __restrict__ gamd, const float* __restrict__ betd,
                        float* __restrict__ bnp, int N) {
  int i = threadIdx.x;  // 128
  float invN = 1.f / (float)N;
  {
    float mu = gstats[i] * invN;
    float var = gstats[128 + i] * invN - mu * mu;
    float sc = gamn[i] * rsqrtf(var + 1e-5f);
    bnp[i] = sc;
    bnp[128 + i] = betn[i] - mu * sc;
  }
  {
    float mu = gstats[256 + i] * invN;
    float var = gstats[384 + i] * invN - mu * mu;
    float sc = gamd[i] * rsqrtf(var + 1e-5f);
    bnp[256 + i] = sc;
    bnp[384 + i] = betd[i] - mu * sc;
  }
}

// ---------------- stage 2: one LDS tile/wave, f32 running sum in regs ----------------
// Phases: xx GEMM -> tile -> gate0 | xn GEMM (sum+=) -> tile -> gate1
//         | xd GEMM -> tile -> gate2 | softmax+cumsum, out = sum + flip(xd)*g
__global__ __launch_bounds__(256) void fuse2_k(
    const uint16_t* __restrict__ xb, const uint16_t* __restrict__ h1n,
    const uint16_t* __restrict__ h1d, const uint16_t* __restrict__ wbf,
    const float* __restrict__ bnp, const float* __restrict__ b_sl,
    const float* __restrict__ b2n, const float* __restrict__ b2d,
    const float* __restrict__ bgat, float* __restrict__ out, int N) {
  __shared__ __align__(16) uint16_t smt[4][16][136];  // ONE per-wave tile, reused 3x
  const int tid = threadIdx.x;
  const int lane = tid & 63, w = tid >> 6;
  const int lr = lane & 15, lg = lane >> 4;
  const int rowbase = blockIdx.x * 64 + w * 16;
  const int arow = min(rowbase + lr, N - 1);
  const uint16_t* wg = wbf + 5 * 16384;

  f4_t sum[8];   // f32 running x_new_x + x_new_n (with biases)
  f4_t accG[8];  // gate logits (minus bgat)
  const f4_t zz = {0.f, 0.f, 0.f, 0.f};

  // ---- phase A: xx = xb @ wsl.T + b_sl -> sum, tile ----
#pragma unroll
  for (int t = 0; t < 8; ++t) sum[t] = zz;
#pragma unroll
  for (int s = 0; s < 4; ++s) {
    const int k0 = s * 32 + lg * 8;
    bf8_t a = *(const bf8_t*)(xb + (size_t)arow * FF + k0);
#pragma unroll
    for (int t = 0; t < 8; ++t) {
      bf8_t b = *(const bf8_t*)(wbf + (size_t)(t * 16 + lr) * FF + k0);
      sum[t] = __builtin_amdgcn_mfma_f32_16x16x32_bf16(a, b, sum[t], 0, 0, 0);
    }
  }
#pragma unroll
  for (int t = 0; t < 8; ++t) {
    const int col = t * 16 + lr;
    const float b = b_sl[col];
#pragma unroll
    for (int r = 0; r < 4; ++r) {
      sum[t][r] += b;
      smt[w][lg * 4 + r][col] = f2bf(sum[t][r]);
    }
  }

  // ---- phase B: gate partial, src 0 (xx) ----
#pragma unroll
  for (int t = 0; t < 8; ++t) accG[t] = zz;
#pragma unroll
  for (int s = 0; s < 4; ++s) {
    const int k0 = s * 32 + lg * 8;
    bf8_t a = *(const bf8_t*)&smt[w][lr][k0];
#pragma unroll
    for (int t = 0; t < 8; ++t) {
      bf8_t b = *(const bf8_t*)(wg + (size_t)(t * 16 + lr) * 384 + k0);
      accG[t] = __builtin_amdgcn_mfma_f32_16x16x32_bf16(a, b, accG[t], 0, 0, 0);
    }
  }

  // ---- phases C..F: branch GEMM2 + gate partial, br = 0 (xn), 1 (xd) ----
#pragma unroll 1
  for (int br = 0; br < 2; ++br) {
    const uint16_t* hp = br ? h1d : h1n;
    const float* bnb = bnp + br * 256;
    const uint16_t* wp = wbf + (br ? 4 : 2) * 16384;
    const float* bp = br ? b2d : b2n;
    f4_t wk[8];
#pragma unroll
    for (int t = 0; t < 8; ++t) wk[t] = zz;
#pragma unroll
    for (int s = 0; s < 4; ++s) {
      const int k0 = s * 32 + lg * 8;
      f4_t sc0 = *(const f4_t*)(bnb + k0), sc1 = *(const f4_t*)(bnb + k0 + 4);
      f4_t sh0 = *(const f4_t*)(bnb + 128 + k0), sh1 = *(const f4_t*)(bnb + 128 + k0 + 4);
      us8_t h = *(const us8_t*)(hp + (size_t)arow * FF + k0);
      bf8_t a;
#pragma unroll
      for (int j = 0; j < 4; ++j) {
        a[j] = (short)f2bf(fmaxf(bf2f(h[j]) * sc0[j] + sh0[j], 0.f));
        a[j + 4] = (short)f2bf(fmaxf(bf2f(h[j + 4]) * sc1[j] + sh1[j], 0.f));
      }
#pragma unroll
      for (int t = 0; t < 8; ++t) {
        bf8_t b = *(const bf8_t*)(wp + (size_t)(t * 16 + lr) * FF + k0);
        wk[t] = __builtin_amdgcn_mfma_f32_16x16x32_bf16(a, b, wk[t], 0, 0, 0);
      }
    }
    // bias; xn adds into running sum; both write the shared tile
#pragma unroll
    for (int t = 0; t < 8; ++t) {
      const int col = t * 16 + lr;
      const float b = bp[col];
#pragma unroll
      for (int r = 0; r < 4; ++r) {
        const float v = wk[t][r] + b;
        if (br == 0) sum[t][r] += v;
        smt[w][lg * 4 + r][col] = f2bf(v);
      }
    }
    // gate partial, src 1+br
#pragma unroll
    for (int s = 0; s < 4; ++s) {
      const int k0 = s * 32 + lg * 8;
      bf8_t a = *(const bf8_t*)&smt[w][lr][k0];
#pragma unroll
      for (int t = 0; t < 8; ++t) {
        bf8_t b = *(const bf8_t*)(wg + (size_t)(t * 16 + lr) * 384 + (1 + br) * FF + k0);
        accG[t] = __builtin_amdgcn_mfma_f32_16x16x32_bf16(a, b, accG[t], 0, 0, 0);
      }
    }
  }

  // ---- softmax + cumsum + output (tile still holds xd) ----
  float bg[8];
#pragma unroll
  for (int t = 0; t < 8; ++t) bg[t] = bgat[t * 16 + lr];
#pragma unroll
  for (int r = 0; r < 4; ++r) {
    float lv[8];
#pragma unroll
    for (int t = 0; t < 8; ++t) lv[t] = accG[t][r] + bg[t];
    float m = lv[0];
#pragma unroll
    for (int t = 1; t < 8; ++t) m = fmaxf(m, lv[t]);
#pragma unroll
    for (int d = 1; d < 16; d <<= 1) m = fmaxf(m, __shfl_xor(m, d, 16));
    float g[8];
    float run = 0.f;
#pragma unroll
    for (int t = 0; t < 8; ++t) {
      float p = __expf(lv[t] - m);
      float scn = p;
#pragma unroll
      for (int d = 1; d < 16; d <<= 1) {
        float o = __shfl_up(scn, (unsigned)d, 16);
        if (lr >= d) scn += o;
      }
      g[t] = run + scn;
      run += __shfl(scn, 15, 16);
    }
    const float inv = 1.f / run;
    const int row = rowbase + lg * 4 + r;
    if (row < N) {
      const int lrow = lg * 4 + r;
#pragma unroll
      for (int t = 0; t < 8; ++t) {
        const int col = t * 16 + lr;
        const float xdf = bf2f(smt[w][lrow][127 - col]);
        out[(size_t)row * FF + col] = sum[t][r] + xdf * (g[t] * inv);
      }
    }
  }
}

extern "C" void kernel_launch(void* const* d_in, const int* in_sizes, int n_in,
                              void* d_out, int out_size, void* d_ws, size_t ws_size,
                              hipStream_t stream) {
  const float* x = (const float*)d_in[0];
  const int* eidx = (const int*)d_in[1];
  const int* etype = (const int*)d_in[2];
  const float* w_sl = (const float*)d_in[3];
  const float* b_sl = (const float*)d_in[4];
  const float* w1n = (const float*)d_in[5];
  const float* b1n = (const float*)d_in[6];
  const float* gamn = (const float*)d_in[7];
  const float* betn = (const float*)d_in[8];
  const float* w2n = (const float*)d_in[9];
  const float* b2n = (const float*)d_in[10];
  const float* w1d = (const float*)d_in[11];
  const float* b1d = (const float*)d_in[12];
  const float* gamd = (const float*)d_in[13];
  const float* betd = (const float*)d_in[14];
  const float* w2d = (const float*)d_in[15];
  const float* b2d = (const float*)d_in[16];
  const float* wgat = (const float*)d_in[17];
  const float* bgat = (const float*)d_in[18];
  float* out = (float*)d_out;

  const int N = in_sizes[0] / FF;
  const int E = in_sizes[2];
  const int* src = eidx;
  const int* dst = eidx + E;
  const int nbins = 2 * N;

  const size_t NF = (size_t)N * FF;
  float* gstats = (float*)d_ws;
  float* bnp = gstats + 512;
  uint16_t* wbf = (uint16_t*)(bnp + 512);  // 131072 u16
  uint16_t* xb = wbf + 131072;             // NF
  uint16_t* xanb = xb + NF;
  uint16_t* xadb = xanb + NF;
  uint16_t* h1n = xadb + NF;
  uint16_t* h1d = h1n + NF;
  int* hist = (int*)(h1d + NF);
  int* off = hist + nbins;     // nbins+1
  int* cur = off + nbins + 1;  // nbins
  int* bsum = cur + nbins;     // <=1024
  int* ssrc = bsum + 1024;     // E

  const int nb1 = (nbins + 255) / 256;

  hipMemsetAsync(hist, 0, (size_t)nbins * sizeof(int), stream);
  hipMemsetAsync(gstats, 0, 512 * sizeof(float), stream);
  cvt_w_k<<<512, 256, 0, stream>>>(w_sl, w1n, w2n, w1d, w2d, wgat, wbf);
  cvt_x_k<<<(int)((NF / 4 + 255) / 256), 256, 0, stream>>>(x, xb, (int)(NF / 4));

  hist_k<<<(E + 255) / 256, 256, 0, stream>>>(dst, etype, hist, E);
  scan1_k<<<nb1, 256, 0, stream>>>(hist, off, bsum, nbins);
  scan2_k<<<1, 1024, 0, stream>>>(bsum, nb1);
  scan3_k<<<(nbins + 256) / 256, 256, 0, stream>>>(off, cur, bsum, nbins, E);
  sctidx_k<<<(E + 255) / 256, 256, 0, stream>>>(src, dst, etype, cur, ssrc, E);
  agg_k<<<(nbins + 3) / 4, 256, 0, stream>>>(off, ssrc, xb, x, xanb, xadb, nbins);

  gemm1_k<<<(N + 127) / 128, 256, 0, stream>>>(xanb, xadb, wbf, b1n, b1d, h1n, h1d,
                                               gstats, N);
  bnfin_k<<<1, 128, 0, stream>>>(gstats, gamn, betn, gamd, betd, bnp, N);
  fuse2_k<<<(N + 63) / 64, 256, 0, stream>>>(xb, h1n, h1d, wbf, bnp, b_sl, b2n, b2d,
                                             bgat, out, N);
}

// Round 6
// 449.008 us; speedup vs baseline: 1.6481x; 1.2919x over previous
//
#include <hip/hip_runtime.h>
#include <stdint.h>

#define FF 128
#define MFMA __builtin_amdgcn_mfma_f32_16x16x32_bf16

typedef __attribute__((ext_vector_type(8))) short bf8_t;     // 8 x bf16 MFMA frag
typedef __attribute__((ext_vector_type(4))) float f4_t;      // MFMA acc
typedef __attribute__((ext_vector_type(8))) uint16_t us8_t;  // 8 x bf16 bits

__device__ __forceinline__ uint16_t f2bf(float f) {
  union { float f; uint32_t u; } v; v.f = f;
  return (uint16_t)((v.u + 0x7fffu + ((v.u >> 16) & 1u)) >> 16);  // RNE
}
__device__ __forceinline__ float bf2f(uint16_t h) {
  union { uint32_t u; float f; } v; v.u = ((uint32_t)h) << 16;
  return v.f;
}

// Stage one 128x128 bf16 weight matrix (32KB) into LDS, chunk-major:
// wlds byte layout: c*2048 + r*16, c = 16B-col-chunk (0..15), r = row (0..127).
// Fragment read (row t*16+lr, chunk s*4+lg) is bank-conflict-free: bank = 4*lr mod 32,
// 8 lanes per 4-bank group x 16B = exactly the 8-clock floor for 1KB.
#define STAGE_W(Wp, rsb, cb)                                                   \
  do {                                                                         \
    uint4 tmp_[8];                                                             \
    _Pragma("unroll") for (int j_ = 0; j_ < 8; ++j_) {                         \
      int k_ = j_ * 4 + w;                                                     \
      int r_ = ((k_ & 1) << 6) + lane;                                         \
      int c_ = k_ >> 1;                                                        \
      tmp_[j_] = *(const uint4*)((const char*)(Wp) + (size_t)r_ * (rsb) +      \
                                 (cb) + c_ * 16);                              \
    }                                                                          \
    _Pragma("unroll") for (int j_ = 0; j_ < 8; ++j_) {                         \
      int k_ = j_ * 4 + w;                                                     \
      *(uint4*)((char*)wlds + k_ * 1024 + lane * 16) = tmp_[j_];               \
    }                                                                          \
  } while (0)

// ---------------- weights f32 -> bf16 ----------------
// layout: [wsl | w1n | w2n | w1d | w2d] each 128x128, then wgat 128x384
__global__ __launch_bounds__(256) void cvt_w_k(
    const float* __restrict__ wsl, const float* __restrict__ w1n,
    const float* __restrict__ w2n, const float* __restrict__ w1d,
    const float* __restrict__ w2d, const float* __restrict__ wgat,
    uint16_t* __restrict__ o) {
  int i = blockIdx.x * 256 + threadIdx.x;
  const int NW = 5 * 16384;
  if (i >= NW + 49152) return;
  float v;
  if (i < NW) {
    int wsel = i >> 14, j = i & 16383;
    const float* p = (wsel == 0) ? wsl : (wsel == 1) ? w1n : (wsel == 2) ? w2n
                     : (wsel == 3) ? w1d : w2d;
    v = p[j];
  } else {
    v = wgat[i - NW];
  }
  o[i] = f2bf(v);
}

// ---------------- x f32 -> bf16 ----------------
__global__ __launch_bounds__(256) void cvt_x_k(const float* __restrict__ x,
                                               uint16_t* __restrict__ xb, int n4) {
  int i = blockIdx.x * 256 + threadIdx.x;
  if (i >= n4) return;
  float4 v = ((const float4*)x)[i];
  uint2 o;
  o.x = ((uint32_t)f2bf(v.y) << 16) | f2bf(v.x);
  o.y = ((uint32_t)f2bf(v.w) << 16) | f2bf(v.z);
  ((uint2*)xb)[i] = o;
}

// ---------------- counting sort of edges by key = dst*2 + type ----------------
__global__ __launch_bounds__(256) void hist_k(const int* __restrict__ dst,
                                              const int* __restrict__ ety,
                                              int* __restrict__ hist, int E) {
  int i = blockIdx.x * 256 + threadIdx.x;
  if (i < E) atomicAdd(&hist[(dst[i] << 1) | ety[i]], 1);
}

__global__ __launch_bounds__(256) void scan1_k(const int* __restrict__ hist,
                                               int* __restrict__ off,
                                               int* __restrict__ bsum, int nbins) {
  int i = blockIdx.x * 256 + threadIdx.x;
  int v = (i < nbins) ? hist[i] : 0;
  int lane = threadIdx.x & 63, w = threadIdx.x >> 6;
  int s = v;
#pragma unroll
  for (int d = 1; d < 64; d <<= 1) {
    int o = __shfl_up(s, (unsigned)d, 64);
    if (lane >= d) s += o;
  }
  __shared__ int wsum[4];
  if (lane == 63) wsum[w] = s;
  __syncthreads();
  int add = 0;
  for (int k = 0; k < w; ++k) add += wsum[k];
  s += add;
  if (i < nbins) off[i] = s - v;  // exclusive
  if (threadIdx.x == 255) bsum[blockIdx.x] = s;
}

__global__ __launch_bounds__(1024) void scan2_k(int* __restrict__ bsum, int nb) {
  int t = threadIdx.x;
  int v = (t < nb) ? bsum[t] : 0;
  int lane = t & 63, w = t >> 6;
  int s = v;
#pragma unroll
  for (int d = 1; d < 64; d <<= 1) {
    int o = __shfl_up(s, (unsigned)d, 64);
    if (lane >= d) s += o;
  }
  __shared__ int ws[16];
  if (lane == 63) ws[w] = s;
  __syncthreads();
  int add = 0;
  for (int k = 0; k < w; ++k) add += ws[k];
  s += add;
  if (t < nb) bsum[t] = s - v;
}

__global__ __launch_bounds__(256) void scan3_k(int* __restrict__ off,
                                               int* __restrict__ cur,
                                               const int* __restrict__ bsum,
                                               int nbins, int E) {
  int i = blockIdx.x * 256 + threadIdx.x;
  if (i < nbins) {
    int v = off[i] + bsum[blockIdx.x];
    off[i] = v;
    cur[i] = v;
  }
  if (i == nbins) off[i] = E;
}

__global__ __launch_bounds__(256) void sctidx_k(const int* __restrict__ src,
                                                const int* __restrict__ dst,
                                                const int* __restrict__ ety,
                                                int* __restrict__ cur,
                                                int* __restrict__ ssrc, int E) {
  int i = blockIdx.x * 256 + threadIdx.x;
  if (i < E) {
    int pos = atomicAdd(&cur[(dst[i] << 1) | ety[i]], 1);
    ssrc[pos] = src[i];
  }
}

// ---------------- segment-sum (bf16 gather) + own row: emits bf16 (x+agg) ----------------
__global__ __launch_bounds__(256) void agg_k(const int* __restrict__ off,
                                             const int* __restrict__ ssrc,
                                             const uint16_t* __restrict__ xb,
                                             const float* __restrict__ x,
                                             uint16_t* __restrict__ xanb,
                                             uint16_t* __restrict__ xadb, int nbins) {
  int wid = (blockIdx.x * 256 + threadIdx.x) >> 6;
  int lane = threadIdx.x & 63;
  if (wid >= nbins) return;
  int e = off[wid], end = off[wid + 1];
  float ax = 0.f, ay = 0.f, bx = 0.f, by = 0.f;
  // 8-deep unroll: 8 independent row loads in flight (avg segment = 8 edges)
  for (; e + 7 < end; e += 8) {
    uint32_t v0 = ((const uint32_t*)(xb + (size_t)ssrc[e] * FF))[lane];
    uint32_t v1 = ((const uint32_t*)(xb + (size_t)ssrc[e + 1] * FF))[lane];
    uint32_t v2 = ((const uint32_t*)(xb + (size_t)ssrc[e + 2] * FF))[lane];
    uint32_t v3 = ((const uint32_t*)(xb + (size_t)ssrc[e + 3] * FF))[lane];
    uint32_t v4 = ((const uint32_t*)(xb + (size_t)ssrc[e + 4] * FF))[lane];
    uint32_t v5 = ((const uint32_t*)(xb + (size_t)ssrc[e + 5] * FF))[lane];
    uint32_t v6 = ((const uint32_t*)(xb + (size_t)ssrc[e + 6] * FF))[lane];
    uint32_t v7 = ((const uint32_t*)(xb + (size_t)ssrc[e + 7] * FF))[lane];
    ax += bf2f((uint16_t)(v0 & 0xffffu)) + bf2f((uint16_t)(v2 & 0xffffu)) +
          bf2f((uint16_t)(v4 & 0xffffu)) + bf2f((uint16_t)(v6 & 0xffffu));
    ay += bf2f((uint16_t)(v0 >> 16)) + bf2f((uint16_t)(v2 >> 16)) +
          bf2f((uint16_t)(v4 >> 16)) + bf2f((uint16_t)(v6 >> 16));
    bx += bf2f((uint16_t)(v1 & 0xffffu)) + bf2f((uint16_t)(v3 & 0xffffu)) +
          bf2f((uint16_t)(v5 & 0xffffu)) + bf2f((uint16_t)(v7 & 0xffffu));
    by += bf2f((uint16_t)(v1 >> 16)) + bf2f((uint16_t)(v3 >> 16)) +
          bf2f((uint16_t)(v5 >> 16)) + bf2f((uint16_t)(v7 >> 16));
  }
  for (; e + 1 < end; e += 2) {
    uint32_t v0 = ((const uint32_t*)(xb + (size_t)ssrc[e] * FF))[lane];
    uint32_t v1 = ((const uint32_t*)(xb + (size_t)ssrc[e + 1] * FF))[lane];
    ax += bf2f((uint16_t)(v0 & 0xffffu));
    ay += bf2f((uint16_t)(v0 >> 16));
    bx += bf2f((uint16_t)(v1 & 0xffffu));
    by += bf2f((uint16_t)(v1 >> 16));
  }
  if (e < end) {
    uint32_t v0 = ((const uint32_t*)(xb + (size_t)ssrc[e] * FF))[lane];
    ax += bf2f((uint16_t)(v0 & 0xffffu));
    ay += bf2f((uint16_t)(v0 >> 16));
  }
  ax += bx;
  ay += by;
  int n = wid >> 1;
  float2 xo = ((const float2*)(x + (size_t)n * FF))[lane];
  ax += xo.x;
  ay += xo.y;
  uint32_t o = ((uint32_t)f2bf(ay) << 16) | f2bf(ax);
  uint16_t* dstp = (wid & 1) ? xadb : xanb;
  ((uint32_t*)(dstp + (size_t)n * FF))[lane] = o;
}

// ---------------- stage 1: branch GEMM1s, weights staged in LDS + BN stats ----------------
__global__ __launch_bounds__(256) void gemm1_k(
    const uint16_t* __restrict__ xanb, const uint16_t* __restrict__ xadb,
    const uint16_t* __restrict__ wbf, const float* __restrict__ b1n,
    const float* __restrict__ b1d, uint16_t* __restrict__ h1n,
    uint16_t* __restrict__ h1d, float* __restrict__ gstats, int N) {
  __shared__ __align__(16) uint16_t wlds[16384];
  __shared__ float sstat[4][4][128];
  const int tid = threadIdx.x;
  const int lane = tid & 63, w = tid >> 6;
  const int lr = lane & 15, lg = lane >> 4;
  const int rowbase = blockIdx.x * 128 + w * 32;
  const int arow0 = min(rowbase + lr, N - 1);
  const int arow1 = min(rowbase + 16 + lr, N - 1);

  f4_t acc[2][8];
  const f4_t zz = {0.f, 0.f, 0.f, 0.f};
  bf8_t a0[4], a1[4];

  // stage w1n; A-loads (branch n) issue under the stage
  STAGE_W(wbf + 16384, 256, 0);
#pragma unroll
  for (int s = 0; s < 4; ++s) {
    const int k0 = s * 32 + lg * 8;
    a0[s] = *(const bf8_t*)(xanb + (size_t)arow0 * FF + k0);
    a1[s] = *(const bf8_t*)(xanb + (size_t)arow1 * FF + k0);
  }
  __syncthreads();

#pragma unroll 1
  for (int gi = 0; gi < 2; ++gi) {
#pragma unroll
    for (int rg = 0; rg < 2; ++rg)
#pragma unroll
      for (int t = 0; t < 8; ++t) acc[rg][t] = zz;
#pragma unroll
    for (int s = 0; s < 4; ++s) {
#pragma unroll
      for (int t = 0; t < 8; ++t) {
        bf8_t b = *(const bf8_t*)&wlds[(s * 4 + lg) * 1024 + (t * 16 + lr) * 8];
        acc[0][t] = MFMA(a0[s], b, acc[0][t], 0, 0, 0);
        acc[1][t] = MFMA(a1[s], b, acc[1][t], 0, 0, 0);
      }
    }
    const float* bp = gi ? b1d : b1n;
    uint16_t* hp = gi ? h1d : h1n;
#pragma unroll
    for (int t = 0; t < 8; ++t) {
      const int col = t * 16 + lr;
      const float b = bp[col];
      float sum = 0.f, ss = 0.f;
#pragma unroll
      for (int rg = 0; rg < 2; ++rg)
#pragma unroll
        for (int r = 0; r < 4; ++r) {
          const int row = rowbase + rg * 16 + lg * 4 + r;
          const float h = acc[rg][t][r] + b;
          if (row < N) {
            hp[(size_t)row * FF + col] = f2bf(h);
            sum += h;
            ss += h * h;
          }
        }
      sum += __shfl_xor(sum, 16, 64);
      sum += __shfl_xor(sum, 32, 64);
      ss += __shfl_xor(ss, 16, 64);
      ss += __shfl_xor(ss, 32, 64);
      if (lane < 16) {
        sstat[w][gi * 2 + 0][col] = sum;
        sstat[w][gi * 2 + 1][col] = ss;
      }
    }
    if (gi == 0) {
      __syncthreads();  // all waves done reading w1n
      STAGE_W(wbf + 3 * 16384, 256, 0);
#pragma unroll
      for (int s = 0; s < 4; ++s) {
        const int k0 = s * 32 + lg * 8;
        a0[s] = *(const bf8_t*)(xadb + (size_t)arow0 * FF + k0);
        a1[s] = *(const bf8_t*)(xadb + (size_t)arow1 * FF + k0);
      }
      __syncthreads();
    }
  }
  __syncthreads();
  for (int i = tid; i < 512; i += 256) {
    int a = i >> 7, c = i & 127;
    float v = sstat[0][a][c] + sstat[1][a][c] + sstat[2][a][c] + sstat[3][a][c];
    unsafeAtomicAdd(&gstats[i], v);
  }
}

// ---------------- BN finalize ----------------
__global__ void bnfin_k(const float* __restrict__ gstats,
                        const float* __restrict__ gamn, const float* __restrict__ betn,
                        const float* __restrict__ gamd, const float* __restrict__ betd,
                        float* __restrict__ bnp, int N) {
  int i = threadIdx.x;  // 128
  float invN = 1.f / (float)N;
  {
    float mu = gstats[i] * invN;
    float var = gstats[128 + i] * invN - mu * mu;
    float sc = gamn[i] * rsqrtf(var + 1e-5f);
    bnp[i] = sc;
    bnp[128 + i] = betn[i] - mu * sc;
  }
  {
    float mu = gstats[256 + i] * invN;
    float var = gstats[384 + i] * invN - mu * mu;
    float sc = gamd[i] * rsqrtf(var + 1e-5f);
    bnp[256 + i] = sc;
    bnp[384 + i] = betd[i] - mu * sc;
  }
}

// ---------------- stage 2: 6 staged weight phases, B from LDS ----------------
__global__ __launch_bounds__(256) void fuse2_k(
    const uint16_t* __restrict__ xb, const uint16_t* __restrict__ h1n,
    const uint16_t* __restrict__ h1d, const uint16_t* __restrict__ wbf,
    const float* __restrict__ bnp, const float* __restrict__ b_sl,
    const float* __restrict__ b2n, const float* __restrict__ b2d,
    const float* __restrict__ bgat, float* __restrict__ out, int N) {
  __shared__ __align__(16) uint16_t wlds[16384];      // staged weight (32KB)
  __shared__ __align__(16) uint16_t smt[4][16][136];  // per-wave tile, reused 3x
  const int tid = threadIdx.x;
  const int lane = tid & 63, w = tid >> 6;
  const int lr = lane & 15, lg = lane >> 4;
  const int rowbase = blockIdx.x * 64 + w * 16;
  const int arow = min(rowbase + lr, N - 1);
  const uint16_t* wg = wbf + 5 * 16384;

  f4_t sum[8];   // f32 running x_new_x + x_new_n (with biases)
  f4_t accG[8];  // gate logits (minus bgat)
  f4_t wk[8];
  const f4_t zz = {0.f, 0.f, 0.f, 0.f};

#define GATE_PHASE()                                                             \
  do {                                                                          \
    _Pragma("unroll") for (int s = 0; s < 4; ++s) {                             \
      bf8_t a = *(const bf8_t*)&smt[w][lr][s * 32 + lg * 8];                    \
      _Pragma("unroll") for (int t = 0; t < 8; ++t) {                           \
        bf8_t b = *(const bf8_t*)&wlds[(s * 4 + lg) * 1024 + (t * 16 + lr) * 8]; \
        accG[t] = MFMA(a, b, accG[t], 0, 0, 0);                                 \
      }                                                                         \
    }                                                                           \
  } while (0)

#define BRANCH_PHASE(hv, bnb, bp, ADDSUM)                                        \
  do {                                                                          \
    _Pragma("unroll") for (int t = 0; t < 8; ++t) wk[t] = zz;                   \
    _Pragma("unroll") for (int s = 0; s < 4; ++s) {                             \
      const int k0 = s * 32 + lg * 8;                                           \
      f4_t sc0 = *(const f4_t*)((bnb) + k0);                                    \
      f4_t sc1 = *(const f4_t*)((bnb) + k0 + 4);                                \
      f4_t sh0 = *(const f4_t*)((bnb) + 128 + k0);                              \
      f4_t sh1 = *(const f4_t*)((bnb) + 128 + k0 + 4);                          \
      bf8_t a;                                                                  \
      _Pragma("unroll") for (int j = 0; j < 4; ++j) {                           \
        a[j] = (short)f2bf(fmaxf(bf2f((hv)[s][j]) * sc0[j] + sh0[j], 0.f));     \
        a[j + 4] =                                                              \
            (short)f2bf(fmaxf(bf2f((hv)[s][j + 4]) * sc1[j] + sh1[j], 0.f));    \
      }                                                                         \
      _Pragma("unroll") for (int t = 0; t < 8; ++t) {                           \
        bf8_t b = *(const bf8_t*)&wlds[(s * 4 + lg) * 1024 + (t * 16 + lr) * 8]; \
        wk[t] = MFMA(a, b, wk[t], 0, 0, 0);                                     \
      }                                                                         \
    }                                                                           \
    _Pragma("unroll") for (int t = 0; t < 8; ++t) {                             \
      const int col = t * 16 + lr;                                              \
      const float bb = (bp)[col];                                               \
      _Pragma("unroll") for (int r = 0; r < 4; ++r) {                           \
        const float v = wk[t][r] + bb;                                          \
        if (ADDSUM) sum[t][r] += v;                                             \
        smt[w][lg * 4 + r][col] = f2bf(v);                                      \
      }                                                                         \
    }                                                                           \
  } while (0)

  // hoist xb row fragments (in flight under first stage)
  bf8_t xa[4];
#pragma unroll
  for (int s = 0; s < 4; ++s)
    xa[s] = *(const bf8_t*)(xb + (size_t)arow * FF + s * 32 + lg * 8);

  STAGE_W(wbf, 256, 0);  // wsl
  __syncthreads();

  // ---- phase xx ----
#pragma unroll
  for (int t = 0; t < 8; ++t) sum[t] = zz;
#pragma unroll
  for (int s = 0; s < 4; ++s) {
#pragma unroll
    for (int t = 0; t < 8; ++t) {
      bf8_t b = *(const bf8_t*)&wlds[(s * 4 + lg) * 1024 + (t * 16 + lr) * 8];
      sum[t] = MFMA(xa[s], b, sum[t], 0, 0, 0);
    }
  }
#pragma unroll
  for (int t = 0; t < 8; ++t) {
    const int col = t * 16 + lr;
    const float b = b_sl[col];
#pragma unroll
    for (int r = 0; r < 4; ++r) {
      sum[t][r] += b;
      smt[w][lg * 4 + r][col] = f2bf(sum[t][r]);
    }
  }
  // hoist h1n row (hides under gate0)
  us8_t hvn[4];
#pragma unroll
  for (int s = 0; s < 4; ++s)
    hvn[s] = *(const us8_t*)(h1n + (size_t)arow * FF + s * 32 + lg * 8);

  __syncthreads();
  STAGE_W(wg, 768, 0);  // wgat block 0
  __syncthreads();
#pragma unroll
  for (int t = 0; t < 8; ++t) accG[t] = zz;
  GATE_PHASE();

  __syncthreads();
  STAGE_W(wbf + 2 * 16384, 256, 0);  // w2n
  __syncthreads();
  BRANCH_PHASE(hvn, bnp, b2n, 1);
  // hoist h1d row (hides under gate1)
  us8_t hvd[4];
#pragma unroll
  for (int s = 0; s < 4; ++s)
    hvd[s] = *(const us8_t*)(h1d + (size_t)arow * FF + s * 32 + lg * 8);

  __syncthreads();
  STAGE_W(wg, 768, 256);  // wgat block 1
  __syncthreads();
  GATE_PHASE();

  __syncthreads();
  STAGE_W(wbf + 4 * 16384, 256, 0);  // w2d
  __syncthreads();
  BRANCH_PHASE(hvd, bnp + 256, b2d, 0);

  __syncthreads();
  STAGE_W(wg, 768, 512);  // wgat block 2
  __syncthreads();
  GATE_PHASE();

  // ---- softmax + cumsum + output (smt holds xd) ----
  float bg[8];
#pragma unroll
  for (int t = 0; t < 8; ++t) bg[t] = bgat[t * 16 + lr];
#pragma unroll
  for (int r = 0; r < 4; ++r) {
    float lv[8];
#pragma unroll
    for (int t = 0; t < 8; ++t) lv[t] = accG[t][r] + bg[t];
    float m = lv[0];
#pragma unroll
    for (int t = 1; t < 8; ++t) m = fmaxf(m, lv[t]);
#pragma unroll
    for (int d = 1; d < 16; d <<= 1) m = fmaxf(m, __shfl_xor(m, d, 16));
    float g[8];
    float run = 0.f;
#pragma unroll
    for (int t = 0; t < 8; ++t) {
      float p = __expf(lv[t] - m);
      float scn = p;
#pragma unroll
      for (int d = 1; d < 16; d <<= 1) {
        float o = __shfl_up(scn, (unsigned)d, 16);
        if (lr >= d) scn += o;
      }
      g[t] = run + scn;
      run += __shfl(scn, 15, 16);
    }
    const float inv = 1.f / run;
    const int row = rowbase + lg * 4 + r;
    if (row < N) {
      const int lrow = lg * 4 + r;
#pragma unroll
      for (int t = 0; t < 8; ++t) {
        const int col = t * 16 + lr;
        const float xdf = bf2f(smt[w][lrow][127 - col]);
        out[(size_t)row * FF + col] = sum[t][r] + xdf * (g[t] * inv);
      }
    }
  }
#undef GATE_PHASE
#undef BRANCH_PHASE
}

extern "C" void kernel_launch(void* const* d_in, const int* in_sizes, int n_in,
                              void* d_out, int out_size, void* d_ws, size_t ws_size,
                              hipStream_t stream) {
  const float* x = (const float*)d_in[0];
  const int* eidx = (const int*)d_in[1];
  const int* etype = (const int*)d_in[2];
  const float* w_sl = (const float*)d_in[3];
  const float* b_sl = (const float*)d_in[4];
  const float* w1n = (const float*)d_in[5];
  const float* b1n = (const float*)d_in[6];
  const float* gamn = (const float*)d_in[7];
  const float* betn = (const float*)d_in[8];
  const float* w2n = (const float*)d_in[9];
  const float* b2n = (const float*)d_in[10];
  const float* w1d = (const float*)d_in[11];
  const float* b1d = (const float*)d_in[12];
  const float* gamd = (const float*)d_in[13];
  const float* betd = (const float*)d_in[14];
  const float* w2d = (const float*)d_in[15];
  const float* b2d = (const float*)d_in[16];
  const float* wgat = (const float*)d_in[17];
  const float* bgat = (const float*)d_in[18];
  float* out = (float*)d_out;

  const int N = in_sizes[0] / FF;
  const int E = in_sizes[2];
  const int* src = eidx;
  const int* dst = eidx + E;
  const int nbins = 2 * N;

  const size_t NF = (size_t)N * FF;
  float* gstats = (float*)d_ws;
  float* bnp = gstats + 512;
  uint16_t* wbf = (uint16_t*)(bnp + 512);  // 131072 u16
  uint16_t* xb = wbf + 131072;             // NF
  uint16_t* xanb = xb + NF;
  uint16_t* xadb = xanb + NF;
  uint16_t* h1n = xadb + NF;
  uint16_t* h1d = h1n + NF;
  int* hist = (int*)(h1d + NF);
  int* off = hist + nbins;     // nbins+1
  int* cur = off + nbins + 1;  // nbins
  int* bsum = cur + nbins;     // <=1024
  int* ssrc = bsum + 1024;     // E

  const int nb1 = (nbins + 255) / 256;

  hipMemsetAsync(hist, 0, (size_t)nbins * sizeof(int), stream);
  hipMemsetAsync(gstats, 0, 512 * sizeof(float), stream);
  cvt_w_k<<<512, 256, 0, stream>>>(w_sl, w1n, w2n, w1d, w2d, wgat, wbf);
  cvt_x_k<<<(int)((NF / 4 + 255) / 256), 256, 0, stream>>>(x, xb, (int)(NF / 4));

  hist_k<<<(E + 255) / 256, 256, 0, stream>>>(dst, etype, hist, E);
  scan1_k<<<nb1, 256, 0, stream>>>(hist, off, bsum, nbins);
  scan2_k<<<1, 1024, 0, stream>>>(bsum, nb1);
  scan3_k<<<(nbins + 256) / 256, 256, 0, stream>>>(off, cur, bsum, nbins, E);
  sctidx_k<<<(E + 255) / 256, 256, 0, stream>>>(src, dst, etype, cur, ssrc, E);
  agg_k<<<(nbins + 3) / 4, 256, 0, stream>>>(off, ssrc, xb, x, xanb, xadb, nbins);

  gemm1_k<<<(N + 127) / 128, 256, 0, stream>>>(xanb, xadb, wbf, b1n, b1d, h1n, h1d,
                                               gstats, N);
  bnfin_k<<<1, 128, 0, stream>>>(gstats, gamn, betn, gamd, betd, bnp, N);
  fuse2_k<<<(N + 63) / 64, 256, 0, stream>>>(xb, h1n, h1d, wbf, bnp, b_sl, b2n, b2d,
                                             bgat, out, N);
}